// Round 1
// baseline (140.331 us; speedup 1.0000x reference)
//
#include <hip/hip_runtime.h>

// SparseConv3D gather rewrite — zero atomics.
//   k0 sp3d_prep : tbl = -1 fill; sp f32->bf16 (ws); W f32->bf16 + transpose to [27][cout][cin] (ws)
//   k1 sp3d_build: tbl[o][out_idx] = in_idx  (plain stores — out_idx unique within an offset)
//   k2 sp3d_main : per 256-row block, loop over 27 taps: double-buffered LDS weight tile,
//                  A-fragments gathered directly from global bf16 (exec-masked), MFMA accumulate
//                  in registers across all taps, single plain store + bias per row.
// Workspace layout (needs ~23.6 MB): spb[N*64 bf16] | wb[27*64*64 bf16] | tbl[26*N int]

typedef __bf16 bf16x8 __attribute__((ext_vector_type(8)));
typedef float f32x4 __attribute__((ext_vector_type(4)));

#define LDSP 72  // padded LDS row stride (bf16 elems): 144B rows -> b128 frag reads ~2-way (free)

__device__ __forceinline__ unsigned short f2bf(float f) {
    union { float f; unsigned int u; } v; v.f = f;
    unsigned int u = v.u;
    return (unsigned short)((u + 0x7FFFu + ((u >> 16) & 1u)) >> 16);  // RNE
}

__device__ __forceinline__ ushort4 cvt4(float4 v) {
    ushort4 b;
    b.x = f2bf(v.x); b.y = f2bf(v.y); b.z = f2bf(v.z); b.w = f2bf(v.w);
    return b;
}

// ---- k0: fill tbl=-1, convert sp and weights to bf16 ----
__global__ __launch_bounds__(256) void sp3d_prep(
    const float* __restrict__ sp, const float* __restrict__ w,
    unsigned short* __restrict__ spb, unsigned short* __restrict__ wb,
    int* __restrict__ tbl, int n_rows)
{
    const long gt = (long)blockIdx.x * 256 + threadIdx.x;
    const long stride = (long)gridDim.x * 256;

    // 1) tbl = -1 (vectorized int4 + scalar tail)
    const long ntbl = 26L * n_rows;
    for (long i = gt; i < (ntbl >> 2); i += stride)
        *(int4*)&tbl[i * 4] = make_int4(-1, -1, -1, -1);
    if (gt < (ntbl & 3)) tbl[(ntbl & ~3L) + gt] = -1;

    // 2) sp f32 -> bf16
    const long nsp = (long)n_rows * 16;  // float4 chunks
    for (long i = gt; i < nsp; i += stride) {
        float4 v = *(const float4*)&sp[i * 4];
        *(ushort4*)&spb[i * 4] = cvt4(v);
    }

    // 3) W [cout][27][cin] f32 -> [tap][cout][cin] bf16
    for (long i = gt; i < 27 * 1024; i += stride) {
        int tp = (int)(i >> 10);
        int r  = (int)(i & 1023);
        int n = r >> 4, k4 = r & 15;
        float4 v = *(const float4*)&w[n * 1728 + tp * 64 + k4 * 4];
        *(ushort4*)&wb[(tp * 64 + n) * 64 + k4 * 4] = cvt4(v);
    }
}

// ---- k1: scatter-build neighbor table (no conflicts within an offset) ----
__global__ __launch_bounds__(256) void sp3d_build(
    const int* __restrict__ nei, const int* __restrict__ sizes,
    int* __restrict__ tbl, int n_rows, int P)
{
    const int o = blockIdx.y;
    const int p = blockIdx.x * 256 + threadIdx.x;
    if (p < sizes[o]) {
        int2 pr = *(const int2*)&nei[(o * P + p) * 2];   // (out_idx, in_idx)
        tbl[(long)o * n_rows + pr.x] = pr.y;
    }
}

// ---- k2: fused gather GEMM over 27 taps, 256 rows/block, 4 waves ----
__global__ __launch_bounds__(256) void sp3d_main(
    const unsigned short* __restrict__ spb, const unsigned short* __restrict__ wb,
    const float* __restrict__ bias, const int* __restrict__ tbl,
    float* __restrict__ out, int n_rows)
{
    __shared__ unsigned short Bt[2][64 * LDSP];  // weight tile double buffer (18.4 KB)
    __shared__ int tl[26][256];                  // this block's neighbor table slice (26.6 KB)

    const int t = threadIdx.x;
    const int row0 = blockIdx.x * 256;
    const int wid = t >> 6, lane = t & 63, ml = lane & 15, quad = lane >> 4;

    // stage neighbor-table slice (tbl is offset-major -> 26 coalesced 1KB loads)
    {
        int r = row0 + t;
        if (r >= n_rows) r = n_rows - 1;
        #pragma unroll
        for (int o = 0; o < 26; ++o)
            tl[o][t] = tbl[(long)o * n_rows + r];
    }
    // stage tap-0 weight tile
    {
        int c = t;
        *(bf16x8*)&Bt[0][(c >> 3) * LDSP + (c & 7) * 8] = *(const bf16x8*)(wb + c * 8);
        c = t + 256;
        *(bf16x8*)&Bt[0][(c >> 3) * LDSP + (c & 7) * 8] = *(const bf16x8*)(wb + c * 8);
    }

    f32x4 acc[4][4];
    #pragma unroll
    for (int mg = 0; mg < 4; ++mg)
        #pragma unroll
        for (int nt = 0; nt < 4; ++nt) acc[mg][nt] = f32x4{0.f, 0.f, 0.f, 0.f};

    __syncthreads();

    int cur = 0;
    for (int tp = 0; tp < 27; ++tp) {
        // B frags for current tap (held in regs, reused by 4 m-groups)
        bf16x8 b0[4], b1[4];
        #pragma unroll
        for (int nt = 0; nt < 4; ++nt) {
            b0[nt] = *(const bf16x8*)&Bt[cur][(nt * 16 + ml) * LDSP + quad * 8];
            b1[nt] = *(const bf16x8*)&Bt[cur][(nt * 16 + ml) * LDSP + 32 + quad * 8];
        }

        // issue next tap's global weight loads early (write-late after compute: T14)
        bf16x8 s0, s1;
        if (tp < 26) {
            const unsigned short* src = wb + (tp + 1) * 4096;
            s0 = *(const bf16x8*)(src + t * 8);
            s1 = *(const bf16x8*)(src + (t + 256) * 8);
        }

        // neighbor index per m-group (center tap = own row)
        int inr[4];
        #pragma unroll
        for (int mg = 0; mg < 4; ++mg) {
            int rl = wid * 64 + mg * 16 + ml;
            if (tp == 13) {
                int r = row0 + rl;
                inr[mg] = (r < n_rows) ? r : n_rows - 1;
            } else {
                int o = tp - (tp > 13 ? 1 : 0);
                inr[mg] = tl[o][rl];
            }
        }

        #pragma unroll
        for (int mg = 0; mg < 4; ++mg) {
            if (__any(inr[mg] >= 0)) {       // skip m-groups with no active neighbor (~46%)
                bf16x8 a0, a1;
                #pragma unroll
                for (int j = 0; j < 8; ++j) { a0[j] = (__bf16)0.f; a1[j] = (__bf16)0.f; }
                if (inr[mg] >= 0) {          // exec-masked gather, invalid lanes stay zero
                    const unsigned short* ap = spb + (long)inr[mg] * 64 + quad * 8;
                    a0 = *(const bf16x8*)ap;
                    a1 = *(const bf16x8*)(ap + 32);
                }
                #pragma unroll
                for (int nt = 0; nt < 4; ++nt) {
                    acc[mg][nt] = __builtin_amdgcn_mfma_f32_16x16x32_bf16(a0, b0[nt], acc[mg][nt], 0, 0, 0);
                    acc[mg][nt] = __builtin_amdgcn_mfma_f32_16x16x32_bf16(a1, b1[nt], acc[mg][nt], 0, 0, 0);
                }
            }
        }

        // write-late: commit next tap's tile to the other LDS buffer
        if (tp < 26) {
            int c = t;
            *(bf16x8*)&Bt[cur ^ 1][(c >> 3) * LDSP + (c & 7) * 8] = s0;
            c = t + 256;
            *(bf16x8*)&Bt[cur ^ 1][(c >> 3) * LDSP + (c & 7) * 8] = s1;
        }
        __syncthreads();
        cur ^= 1;
    }

    // epilogue: bias + single plain store per row (C/D layout: col=lane&15, row=quad*4+reg)
    float bv[4];
    #pragma unroll
    for (int nt = 0; nt < 4; ++nt) bv[nt] = bias[nt * 16 + ml];
    #pragma unroll
    for (int mg = 0; mg < 4; ++mg) {
        int rb = row0 + wid * 64 + mg * 16 + quad * 4;
        #pragma unroll
        for (int nt = 0; nt < 4; ++nt) {
            int col = nt * 16 + ml;
            #pragma unroll
            for (int rg = 0; rg < 4; ++rg) {
                int row = rb + rg;
                if (row < n_rows) out[(long)row * 64 + col] = acc[mg][nt][rg] + bv[nt];
            }
        }
    }
}

extern "C" void kernel_launch(void* const* d_in, const int* in_sizes, int n_in,
                              void* d_out, int out_size, void* d_ws, size_t ws_size,
                              hipStream_t stream) {
    const float* sp    = (const float*)d_in[0];
    const float* w     = (const float*)d_in[1];
    const float* bias  = (const float*)d_in[2];
    const int*   nei   = (const int*)d_in[3];
    const int*   sizes = (const int*)d_in[4];
    float* out = (float*)d_out;

    const int N = in_sizes[0] / 64;
    const int P = in_sizes[3] / (26 * 2);

    // workspace carve-out (256B aligned): spb | wb | tbl  (~23.6 MB total)
    char* ws = (char*)d_ws;
    unsigned short* spb = (unsigned short*)ws;
    size_t off = ((size_t)N * 64 * 2 + 255) & ~(size_t)255;
    unsigned short* wb = (unsigned short*)(ws + off);
    off = (off + 27 * 64 * 64 * 2 + 255) & ~(size_t)255;
    int* tbl = (int*)(ws + off);

    sp3d_prep<<<dim3(1024), 256, 0, stream>>>(sp, w, spb, wb, tbl, N);
    sp3d_build<<<dim3((P + 255) / 256, 26), 256, 0, stream>>>(nei, sizes, tbl, N, P);
    sp3d_main<<<dim3((N + 255) / 256), 256, 0, stream>>>(spb, wb, bias, tbl, out, N);
}

// Round 2
// 132.961 us; speedup vs baseline: 1.0554x; 1.0554x over previous
//
#include <hip/hip_runtime.h>

// SparseConv3D gather, v2 — finer wave granularity for occupancy.
//   k0 sp3d_prep : tbl=-1 fill; sp f32->bf16 (spb); W -> frag-major bf16 wb[tap][frag][lane][8]
//   k1 sp3d_build: tbl[o][out_idx] = in_idx (plain stores; out_idx unique per offset)
//   k2 sp3d_main : 512 thr = 8 waves, 16 rows/wave (128 rows/block), 27 taps:
//                  frag-major LDS weight dbuf (conflict-free linear b128 reads),
//                  A-gather software-pipelined one tap ahead, fp32 reg accumulation,
//                  one plain store per row. Zero atomics.
// Workspace: spb[N*64 bf16] | wb[27*4096 bf16] | tbl[26*N int]  (~23.6 MB)

typedef __bf16 bf16x8 __attribute__((ext_vector_type(8)));
typedef float f32x4 __attribute__((ext_vector_type(4)));

__device__ __forceinline__ unsigned short f2bf(float f) {
    union { float f; unsigned int u; } v; v.f = f;
    unsigned int u = v.u;
    return (unsigned short)((u + 0x7FFFu + ((u >> 16) & 1u)) >> 16);  // RNE
}

__device__ __forceinline__ ushort4 cvt4(float4 v) {
    ushort4 b;
    b.x = f2bf(v.x); b.y = f2bf(v.y); b.z = f2bf(v.z); b.w = f2bf(v.w);
    return b;
}

// ---- k0: fill tbl=-1, sp->bf16, weights -> frag-major bf16 ----
__global__ __launch_bounds__(256) void sp3d_prep(
    const float* __restrict__ sp, const float* __restrict__ w,
    unsigned short* __restrict__ spb, unsigned short* __restrict__ wb,
    int* __restrict__ tbl, int n_rows)
{
    const long gt = (long)blockIdx.x * 256 + threadIdx.x;
    const long stride = (long)gridDim.x * 256;

    const long ntbl = 26L * n_rows;
    for (long i = gt; i < (ntbl >> 2); i += stride)
        *(int4*)&tbl[i * 4] = make_int4(-1, -1, -1, -1);
    if (gt < (ntbl & 3)) tbl[(ntbl & ~3L) + gt] = -1;

    const long nsp = (long)n_rows * 16;  // float4 chunks
    for (long i = gt; i < nsp; i += stride) {
        float4 v = *(const float4*)&sp[i * 4];
        *(ushort4*)&spb[i * 4] = cvt4(v);
    }

    // wb chunk c (bf16x8): c = tap*512 + frag*64 + lane; frag = nt*2+half
    // value[j] = W[cout=nt*16+ml][cin=half*32+quad*8+j], w layout [cout][27][cin]
    for (long i = gt; i < 27 * 512; i += stride) {
        int tap = (int)(i >> 9);
        int rem = (int)(i & 511);
        int fragid = rem >> 6, lane = rem & 63;
        int nt = fragid >> 1, half = fragid & 1, ml = lane & 15, quad = lane >> 4;
        const float* src = w + (nt * 16 + ml) * 1728 + tap * 64 + half * 32 + quad * 8;
        float4 v0 = *(const float4*)src;
        float4 v1 = *(const float4*)(src + 4);
        *(ushort4*)&wb[i * 8]     = cvt4(v0);
        *(ushort4*)&wb[i * 8 + 4] = cvt4(v1);
    }
}

// ---- k1: scatter-build neighbor table (no conflicts within an offset) ----
__global__ __launch_bounds__(256) void sp3d_build(
    const int* __restrict__ nei, const int* __restrict__ sizes,
    int* __restrict__ tbl, int n_rows, int P)
{
    const int o = blockIdx.y;
    const int p = blockIdx.x * 256 + threadIdx.x;
    if (p < sizes[o]) {
        int2 pr = *(const int2*)&nei[(o * P + p) * 2];   // (out_idx, in_idx)
        tbl[(long)o * n_rows + pr.x] = pr.y;
    }
}

// ---- k2: fused gather GEMM, 8 waves x 16 rows, pipelined A-gather ----
__global__ __launch_bounds__(512) void sp3d_main(
    const unsigned short* __restrict__ spb, const unsigned short* __restrict__ wb,
    const float* __restrict__ bias, const int* __restrict__ tbl,
    float* __restrict__ out, int n_rows)
{
    __shared__ unsigned short Bt[2][4096];  // frag-major weight tile dbuf (16 KB)
    __shared__ int tl[26 * 128];            // per-block neighbor slice (13.3 KB)

    const int t = threadIdx.x;
    const int row0 = blockIdx.x * 128;
    const int wid = t >> 6, lane = t & 63, ml = lane & 15, quad = lane >> 4;

    // stage neighbor-table slice (coalesced over rows)
    for (int i = t; i < 26 * 128; i += 512) {
        int o = i >> 7;
        int r = row0 + (i & 127);
        tl[i] = tbl[(long)o * n_rows + (r < n_rows ? r : n_rows - 1)];
    }
    // stage tap-0 weight tile (linear copy, 16B/thread)
    *(bf16x8*)&Bt[0][t * 8] = *(const bf16x8*)(wb + t * 8);

    bf16x8 z8;
    #pragma unroll
    for (int j = 0; j < 8; ++j) z8[j] = (__bf16)0.f;

    // prefetch tap 0 gather (tap 0 -> offset 0)
    int curv = tl[wid * 16 + ml];
    bf16x8 a0 = z8, a1 = z8;
    if (curv >= 0) {
        const unsigned short* ap = spb + (long)curv * 64 + quad * 8;
        a0 = *(const bf16x8*)ap;
        a1 = *(const bf16x8*)(ap + 32);
    }

    f32x4 acc[4];
    #pragma unroll
    for (int nt = 0; nt < 4; ++nt) acc[nt] = f32x4{0.f, 0.f, 0.f, 0.f};

    __syncthreads();

    int cur = 0;
    for (int tp = 0; tp < 27; ++tp) {
        // issue next tap's weight load early (write-late after compute)
        bf16x8 s0 = z8;
        if (tp < 26) s0 = *(const bf16x8*)(wb + (tp + 1) * 4096 + t * 8);

        // prefetch next tap's A fragments (consumed next iteration)
        int ninr = -1;
        bf16x8 na0 = z8, na1 = z8;
        if (tp < 26) {
            int tn = tp + 1;
            if (tn == 13) {
                int r = row0 + wid * 16 + ml;
                ninr = (r < n_rows) ? r : n_rows - 1;
            } else {
                int o = tn - (tn > 13 ? 1 : 0);
                ninr = tl[o * 128 + wid * 16 + ml];
            }
            if (ninr >= 0) {
                const unsigned short* ap = spb + (long)ninr * 64 + quad * 8;
                na0 = *(const bf16x8*)ap;
                na1 = *(const bf16x8*)(ap + 32);
            }
        }

        // MFMA on current tap (skip waves with no active neighbor)
        if (__any(curv >= 0)) {
            #pragma unroll
            for (int nt = 0; nt < 4; ++nt) {
                bf16x8 b0 = *(const bf16x8*)&Bt[cur][(nt * 2 + 0) * 512 + lane * 8];
                bf16x8 b1 = *(const bf16x8*)&Bt[cur][(nt * 2 + 1) * 512 + lane * 8];
                acc[nt] = __builtin_amdgcn_mfma_f32_16x16x32_bf16(a0, b0, acc[nt], 0, 0, 0);
                acc[nt] = __builtin_amdgcn_mfma_f32_16x16x32_bf16(a1, b1, acc[nt], 0, 0, 0);
            }
        }

        // commit next tap's weight tile
        if (tp < 26) *(bf16x8*)&Bt[cur ^ 1][t * 8] = s0;
        __syncthreads();
        a0 = na0; a1 = na1; curv = ninr;
        cur ^= 1;
    }

    // epilogue: bias + single plain store per row (C/D: col=lane&15, row=quad*4+reg)
    #pragma unroll
    for (int nt = 0; nt < 4; ++nt) {
        int col = nt * 16 + ml;
        float bv = bias[col];
        #pragma unroll
        for (int rg = 0; rg < 4; ++rg) {
            int row = row0 + wid * 16 + quad * 4 + rg;
            if (row < n_rows) out[(long)row * 64 + col] = acc[nt][rg] + bv;
        }
    }
}

extern "C" void kernel_launch(void* const* d_in, const int* in_sizes, int n_in,
                              void* d_out, int out_size, void* d_ws, size_t ws_size,
                              hipStream_t stream) {
    const float* sp    = (const float*)d_in[0];
    const float* w     = (const float*)d_in[1];
    const float* bias  = (const float*)d_in[2];
    const int*   nei   = (const int*)d_in[3];
    const int*   sizes = (const int*)d_in[4];
    float* out = (float*)d_out;

    const int N = in_sizes[0] / 64;
    const int P = in_sizes[3] / (26 * 2);

    // workspace carve-out (256B aligned): spb | wb | tbl
    char* ws = (char*)d_ws;
    unsigned short* spb = (unsigned short*)ws;
    size_t off = ((size_t)N * 64 * 2 + 255) & ~(size_t)255;
    unsigned short* wb = (unsigned short*)(ws + off);
    off = (off + 27 * 4096 * 2 + 255) & ~(size_t)255;
    int* tbl = (int*)(ws + off);

    sp3d_prep<<<dim3(2048), 256, 0, stream>>>(sp, w, spb, wb, tbl, N);
    sp3d_build<<<dim3((P + 255) / 256, 26), 256, 0, stream>>>(nei, sizes, tbl, N, P);
    sp3d_main<<<dim3((N + 127) / 128), 512, 0, stream>>>(spb, wb, bias, tbl, out, N);
}